// Round 9
// baseline (531.389 us; speedup 1.0000x reference)
//
#include <hip/hip_runtime.h>

// GCN 2-layer forward on gfx950.
// R19: gemm128 LDS-free retry with the R18 failure fixed: R18's VGPR_Count=48
//      starved the pipeline (serial load->MFMA). Now __launch_bounds__(256,4)
//      (VGPR cap 128) + hand 2-stage pipeline with NAMED next/cur registers:
//      next K-step's 8 loads issue before current step's 8 MFMAs.
//      Everything else identical to R16 (total 400.3): int8 h, bf16 h2,
//      nt-store hagg, XCD remap, inline fp32->bf16 A convert.

typedef unsigned int u32;
typedef unsigned short u16;
typedef __bf16 bf16x8 __attribute__((ext_vector_type(8)));
typedef float f32x4 __attribute__((ext_vector_type(4)));
typedef u32 u32x4 __attribute__((ext_vector_type(4)));

#define C_IN 512
#define C_HID 512
#define C_OUT 40
#define H_SCALE 24.0f
#define H_INV_SCALE (1.0f / 24.0f)

__device__ __forceinline__ float bf2f(u16 u) {
    u32 x = ((u32)u) << 16;
    return __builtin_bit_cast(float, x);
}
__device__ __forceinline__ u16 f2bf(float f) {
    u32 x = __builtin_bit_cast(u32, f);
    x += 0x7fffu + ((x >> 16) & 1u);   // RNE
    return (u16)(x >> 16);
}
__device__ __forceinline__ char q8(float v) {
    float c = fminf(fmaxf(v * H_SCALE, -127.f), 127.f);
    return (char)__float2int_rn(c);
}
__device__ __forceinline__ u32 pk2(float a, float b) {
    u16 lo = __builtin_bit_cast(u16, (__bf16)a);   // RNE, fuses to v_cvt_pk_bf16_f32
    u16 hi = __builtin_bit_cast(u16, (__bf16)b);
    return (u32)lo | ((u32)hi << 16);
}
__device__ __forceinline__ bf16x8 pkfrag(float4 a, float4 b) {
    u32x4 r;
    r.x = pk2(a.x, a.y); r.y = pk2(a.z, a.w);
    r.z = pk2(b.x, b.y); r.w = pk2(b.z, b.w);
    return __builtin_bit_cast(bf16x8, r);
}
__host__ __device__ __forceinline__ int imin(int a, int b) { return a < b ? a : b; }
__host__ __device__ __forceinline__ int imax(int a, int b) { return a > b ? a : b; }

// ---------------- init + dtype detect (fused) ----------------
__global__ void k_init(const u32* __restrict__ x32, const int* __restrict__ ei,
                       int* flags, int* deg, int* cursor, int n) {
    if (blockIdx.x == 0 && threadIdx.x < 64) {
        int lane = threadIdx.x;
        int z = (ei[2 * lane + 1] == 0) ? 1 : 0;
        u32 e = (x32[lane] >> 7) & 0xff;
        int v = (e >= 110 && e <= 133) ? 1 : 0;
        unsigned long long bz = __ballot(z);
        unsigned long long bv = __ballot(v);
        if (lane == 0) {
            flags[0] = (__popcll(bz) == 64) ? 2 : 1;   // int32 step per element
            flags[1] = (__popcll(bv) >= 48) ? 1 : 0;   // floats bf16-packed?
        }
    }
    int i = blockIdx.x * 256 + threadIdx.x;
    if (i < n) { deg[i] = 1; cursor[i] = 0; }          // self-loop
}

__global__ void k_deg(const int* __restrict__ ei, const int* __restrict__ flags,
                      int* deg, int E, int ecap, int n) {
    int e = blockIdx.x * 256 + threadIdx.x;
    if (e >= E) return;
    int st = flags[0];
    int cap = ecap * st - 1;
    u32 d = (u32)ei[imin((E + e) * st, cap)];
    if (d < (u32)n) atomicAdd(&deg[d], 1);
}

// block sums of (deg-1) + dinv (fused)
__global__ void k_scanA(const int* __restrict__ deg, int* bsum, float* dinv, int n) {
    __shared__ int sh[256];
    int i = blockIdx.x * 256 + threadIdx.x;
    int dv = (i < n) ? deg[i] : 1;
    if (i < n) dinv[i] = rsqrtf((float)imax(dv, 1));
    sh[threadIdx.x] = (i < n) ? dv - 1 : 0;
    __syncthreads();
    for (int d = 128; d > 0; d >>= 1) {
        if (threadIdx.x < d) sh[threadIdx.x] += sh[threadIdx.x + d];
        __syncthreads();
    }
    if (threadIdx.x == 0) bsum[blockIdx.x] = sh[0];
}

// parallel exclusive scan of bsum (one 256-thread block, chunked with carry)
__global__ void k_scanB(int* bsum, int nb, int* offs, int n) {
    __shared__ int sh[256];
    int t = threadIdx.x;
    int carry = 0;
    for (int base = 0; base < nb; base += 256) {
        int i = base + t;
        int v = (i < nb) ? bsum[i] : 0;
        sh[t] = v;
        __syncthreads();
        for (int d = 1; d < 256; d <<= 1) {
            int add = (t >= d) ? sh[t - d] : 0;
            __syncthreads();
            sh[t] += add;
            __syncthreads();
        }
        if (i < nb) bsum[i] = carry + sh[t] - v;   // exclusive
        int tot = sh[255];
        __syncthreads();
        carry += tot;
    }
    if (t == 0) offs[n] = carry;
}

__global__ void k_scanC(const int* __restrict__ deg, const int* __restrict__ bsum,
                        int* offs, int n) {
    __shared__ int sh[256];
    int t = threadIdx.x;
    int i = blockIdx.x * 256 + t;
    int v = (i < n) ? deg[i] - 1 : 0;
    sh[t] = v;
    __syncthreads();
    for (int d = 1; d < 256; d <<= 1) {
        int add = (t >= d) ? sh[t - d] : 0;
        __syncthreads();
        sh[t] += add;
        __syncthreads();
    }
    if (i < n) offs[i] = bsum[blockIdx.x] + sh[t] - v;
}

__global__ void k_sort(const int* __restrict__ ei, const int* __restrict__ flags,
                       const int* __restrict__ offs, int* cursor, int* csr,
                       int E, int ecap, int n) {
    int e = blockIdx.x * 256 + threadIdx.x;
    if (e >= E) return;
    int st = flags[0];
    int cap = ecap * st - 1;
    u32 d = (u32)ei[imin((E + e) * st, cap)];
    u32 s = (u32)ei[imin(e * st, cap)];
    if (d < (u32)n && s < (u32)n) {
        int pos = offs[d] + atomicAdd(&cursor[(int)d], 1);
        if ((u32)pos < (u32)E) csr[pos] = (int)s;
    }
}

// ---------------- prep: w1t + w2t + biases only ----------------
__device__ __forceinline__ float ldf(const void* p, int i, int isbf) {
    return isbf ? bf2f(((const u16*)p)[i]) : ((const float*)p)[i];
}

__global__ __launch_bounds__(256) void k_prep(
    const void* __restrict__ W1, const void* __restrict__ b1,
    const void* __restrict__ W2, const void* __restrict__ b2,
    const int* __restrict__ flags, u16* __restrict__ w1t, u16* __restrict__ w2t,
    float* __restrict__ b1f, float* __restrict__ b2f) {
    int isbf = flags[1];
    int stride = gridDim.x * 256;
    int i0 = blockIdx.x * 256 + threadIdx.x;
    for (int i = i0; i < 512 * 512; i += stride) {
        int n = i >> 9, k = i & 511;
        w1t[n * 512 + k] = f2bf(ldf(W1, k * 512 + n, isbf));
    }
    for (int i = i0; i < 64 * 512; i += stride) {
        int n = i >> 9, k = i & 511;
        w2t[i] = (n < C_OUT) ? f2bf(ldf(W2, k * C_OUT + n, isbf)) : (u16)0;
    }
    if (i0 < C_HID) b1f[i0] = ldf(b1, i0, isbf);
    if (i0 < C_OUT) b2f[i0] = ldf(b2, i0, isbf);
}

// ---------------- GEMM1: 64x128, LDS-free, 2-stage named-reg pipeline --------
// Wave w: rows (w&1)*32..+31, cols (w>>1)*64..+63; acc[2][4] (named).
// Per K-step: issue NEXT step's loads (A: 4 float4 or 2 bf16x8; B: 4 bf16x8),
// then 8 MFMA on current frags, then rotate. launch_bounds(256,4) -> VGPR<=128.
__global__ __launch_bounds__(256, 4) void k_gemm128(
    const u16* __restrict__ xbf, const float* __restrict__ xf32,
    const int* __restrict__ flags, const u16* __restrict__ Bt,
    char* __restrict__ C, int M, int K, int ldc) {
    int isbf = flags[1];
    int tid = threadIdx.x;
    int wave = tid >> 6, lane = tid & 63;
    int quad = lane >> 4, lrow = lane & 15;
    int wrow = (wave & 1) * 32, wcol = (wave >> 1) * 64;

    // bijective XCD-chunk remap; 4 consecutive wg share an A row-panel
    int nwg = gridDim.x;
    int id = blockIdx.x;
    int q = nwg >> 3, r = nwg & 7;
    int xcd = id & 7, j8 = id >> 3;
    int wg = (xcd < r ? xcd * (q + 1) : r * (q + 1) + (xcd - r) * q) + j8;
    int row0 = (wg >> 2) * 64;
    int n0 = (wg & 3) * 128;

    int r0i = imin(row0 + wrow + lrow, M - 1);
    int r1i = imin(row0 + wrow + 16 + lrow, M - 1);
    const float* aF0 = xf32 + (size_t)r0i * K + quad * 8;
    const float* aF1 = xf32 + (size_t)r1i * K + quad * 8;
    const u16* aB0 = xbf + (size_t)r0i * K + quad * 8;
    const u16* aB1 = xbf + (size_t)r1i * K + quad * 8;
    const u16* bP0 = Bt + (size_t)(n0 + wcol + 0 * 16 + lrow) * K + quad * 8;
    const u16* bP1 = Bt + (size_t)(n0 + wcol + 1 * 16 + lrow) * K + quad * 8;
    const u16* bP2 = Bt + (size_t)(n0 + wcol + 2 * 16 + lrow) * K + quad * 8;
    const u16* bP3 = Bt + (size_t)(n0 + wcol + 3 * 16 + lrow) * K + quad * 8;

    f32x4 c00 = {}, c01 = {}, c02 = {}, c03 = {};
    f32x4 c10 = {}, c11 = {}, c12 = {}, c13 = {};

    if (isbf) {
        bf16x8 a0 = *(const bf16x8*)(aB0);
        bf16x8 a1 = *(const bf16x8*)(aB1);
        bf16x8 b0 = *(const bf16x8*)(bP0);
        bf16x8 b1 = *(const bf16x8*)(bP1);
        bf16x8 b2 = *(const bf16x8*)(bP2);
        bf16x8 b3 = *(const bf16x8*)(bP3);
#pragma unroll
        for (int k0 = 0; k0 < C_IN; k0 += 32) {
            int kn = (k0 + 32 < C_IN) ? k0 + 32 : 0;   // clamped prefetch (dead on last)
            bf16x8 na0 = *(const bf16x8*)(aB0 + kn);
            bf16x8 na1 = *(const bf16x8*)(aB1 + kn);
            bf16x8 nb0 = *(const bf16x8*)(bP0 + kn);
            bf16x8 nb1 = *(const bf16x8*)(bP1 + kn);
            bf16x8 nb2 = *(const bf16x8*)(bP2 + kn);
            bf16x8 nb3 = *(const bf16x8*)(bP3 + kn);
            c00 = __builtin_amdgcn_mfma_f32_16x16x32_bf16(a0, b0, c00, 0, 0, 0);
            c01 = __builtin_amdgcn_mfma_f32_16x16x32_bf16(a0, b1, c01, 0, 0, 0);
            c02 = __builtin_amdgcn_mfma_f32_16x16x32_bf16(a0, b2, c02, 0, 0, 0);
            c03 = __builtin_amdgcn_mfma_f32_16x16x32_bf16(a0, b3, c03, 0, 0, 0);
            c10 = __builtin_amdgcn_mfma_f32_16x16x32_bf16(a1, b0, c10, 0, 0, 0);
            c11 = __builtin_amdgcn_mfma_f32_16x16x32_bf16(a1, b1, c11, 0, 0, 0);
            c12 = __builtin_amdgcn_mfma_f32_16x16x32_bf16(a1, b2, c12, 0, 0, 0);
            c13 = __builtin_amdgcn_mfma_f32_16x16x32_bf16(a1, b3, c13, 0, 0, 0);
            a0 = na0; a1 = na1; b0 = nb0; b1 = nb1; b2 = nb2; b3 = nb3;
        }
    } else {
        float4 u0 = *(const float4*)(aF0);
        float4 u1 = *(const float4*)(aF0 + 4);
        float4 u2 = *(const float4*)(aF1);
        float4 u3 = *(const float4*)(aF1 + 4);
        bf16x8 b0 = *(const bf16x8*)(bP0);
        bf16x8 b1 = *(const bf16x8*)(bP1);
        bf16x8 b2 = *(const bf16x8*)(bP2);
        bf16x8 b3 = *(const bf16x8*)(bP3);
#pragma unroll
        for (int k0 = 0; k0 < C_IN; k0 += 32) {
            int kn = (k0 + 32 < C_IN) ? k0 + 32 : 0;
            float4 nu0 = *(const float4*)(aF0 + kn);
            float4 nu1 = *(const float4*)(aF0 + kn + 4);
            float4 nu2 = *(const float4*)(aF1 + kn);
            float4 nu3 = *(const float4*)(aF1 + kn + 4);
            bf16x8 nb0 = *(const bf16x8*)(bP0 + kn);
            bf16x8 nb1 = *(const bf16x8*)(bP1 + kn);
            bf16x8 nb2 = *(const bf16x8*)(bP2 + kn);
            bf16x8 nb3 = *(const bf16x8*)(bP3 + kn);
            bf16x8 a0 = pkfrag(u0, u1);
            bf16x8 a1 = pkfrag(u2, u3);
            c00 = __builtin_amdgcn_mfma_f32_16x16x32_bf16(a0, b0, c00, 0, 0, 0);
            c01 = __builtin_amdgcn_mfma_f32_16x16x32_bf16(a0, b1, c01, 0, 0, 0);
            c02 = __builtin_amdgcn_mfma_f32_16x16x32_bf16(a0, b2, c02, 0, 0, 0);
            c03 = __builtin_amdgcn_mfma_f32_16x16x32_bf16(a0, b3, c03, 0, 0, 0);
            c10 = __builtin_amdgcn_mfma_f32_16x16x32_bf16(a1, b0, c10, 0, 0, 0);
            c11 = __builtin_amdgcn_mfma_f32_16x16x32_bf16(a1, b1, c11, 0, 0, 0);
            c12 = __builtin_amdgcn_mfma_f32_16x16x32_bf16(a1, b2, c12, 0, 0, 0);
            c13 = __builtin_amdgcn_mfma_f32_16x16x32_bf16(a1, b3, c13, 0, 0, 0);
            u0 = nu0; u1 = nu1; u2 = nu2; u3 = nu3;
            b0 = nb0; b1 = nb1; b2 = nb2; b3 = nb3;
        }
    }

    f32x4 accv[2][4] = {{c00, c01, c02, c03}, {c10, c11, c12, c13}};
#pragma unroll
    for (int i = 0; i < 2; ++i)
#pragma unroll
        for (int j = 0; j < 4; ++j)
#pragma unroll
            for (int r2i = 0; r2i < 4; ++r2i) {
                int row = row0 + wrow + i * 16 + quad * 4 + r2i;
                int col = n0 + wcol + j * 16 + lrow;
                if (row < M) C[(size_t)row * ldc + col] = q8(accv[i][j][r2i]);
            }
}

// ---------------- GEMM2: 64x64 tile, bf16 out ----------------
__global__ __launch_bounds__(256) void k_gemm64(
    const u16* __restrict__ A, const u16* __restrict__ Bt, u16* __restrict__ Cout,
    int M, int K, int Ncols, int ldc) {
    __shared__ __align__(16) u16 As[64 * 32];
    __shared__ __align__(16) u16 Bs[64 * 32];
    int tid = threadIdx.x;
    int wave = tid >> 6, lane = tid & 63;
    int quad = lane >> 4, lrow = lane & 15;
    int row0 = blockIdx.x * 64;
    int n0 = blockIdx.y * 64;
    int srow = tid >> 2;
    int skc = (tid & 3) * 8;

    f32x4 acc[4] = {};
    int kTiles = K >> 5;
    for (int kt = 0; kt < kTiles; ++kt) {
        int k0 = kt * 32;
        uint4 av = make_uint4(0, 0, 0, 0);
        int gr = row0 + srow;
        if (gr < M) av = *(const uint4*)(A + (size_t)gr * K + k0 + skc);
        uint4 bv = *(const uint4*)(Bt + (size_t)(n0 + srow) * K + k0 + skc);
        __syncthreads();
        *(uint4*)(As + srow * 32 + skc) = av;
        *(uint4*)(Bs + srow * 32 + skc) = bv;
        __syncthreads();
        bf16x8 af = *(const bf16x8*)(As + (wave * 16 + lrow) * 32 + quad * 8);
#pragma unroll
        for (int t = 0; t < 4; ++t) {
            bf16x8 bfr = *(const bf16x8*)(Bs + (t * 16 + lrow) * 32 + quad * 8);
            acc[t] = __builtin_amdgcn_mfma_f32_16x16x32_bf16(af, bfr, acc[t], 0, 0, 0);
        }
    }
#pragma unroll
    for (int t = 0; t < 4; ++t)
#pragma unroll
        for (int r = 0; r < 4; ++r) {
            int row = wave * 16 + quad * 4 + r;
            int col = t * 16 + lrow;
            int gr = row0 + row, gc = n0 + col;
            if (gr < M && gc < Ncols) Cout[(size_t)gr * ldc + gc] = f2bf(acc[t][r]);
        }
}

// ---------------- agg1: hagg = ReLU(Anorm*h + b1), int8 in, bf16 out ----------------
__device__ __forceinline__ void accum8i(float* acc, uint2 p, float w) {
    int lo = (int)p.x, hi = (int)p.y;
    acc[0] += w * (float)(signed char)(lo);
    acc[1] += w * (float)(signed char)(lo >> 8);
    acc[2] += w * (float)(signed char)(lo >> 16);
    acc[3] += w * (float)(signed char)(lo >> 24);
    acc[4] += w * (float)(signed char)(hi);
    acc[5] += w * (float)(signed char)(hi >> 8);
    acc[6] += w * (float)(signed char)(hi >> 16);
    acc[7] += w * (float)(signed char)(hi >> 24);
}

__global__ __launch_bounds__(256) void k_agg1(
    const char* __restrict__ hq, const int* __restrict__ csr, const int* __restrict__ offs,
    const float* __restrict__ dinv, const float* __restrict__ b1f,
    u16* __restrict__ out, int n, int Etot) {
    int wave = threadIdx.x >> 6, lane = threadIdx.x & 63;
    int v = blockIdx.x * 4 + wave;
    if (v >= n) return;
    float dv = dinv[v];
    float wself = dv * dv * H_INV_SCALE;

    float acc[8] = {0.f, 0.f, 0.f, 0.f, 0.f, 0.f, 0.f, 0.f};
    uint2 hs = *(const uint2*)(hq + (size_t)v * C_HID + lane * 8);
    accum8i(acc, hs, wself);

    int e0 = imax(0, imin(offs[v], Etot));
    int e1 = imax(e0, imin(offs[v + 1], Etot));
    for (int base = e0; base < e1; base += 64) {
        int cnt = imin(64, e1 - base);
        int sreg = 0; float wreg = 0.f;
        if (lane < cnt) {
            u32 s = (u32)csr[base + lane];
            s = (s < (u32)n) ? s : 0u;
            sreg = (int)s;
            wreg = dv * dinv[s] * H_INV_SCALE;
        }
        int j = 0;
        for (; j + 16 <= cnt; j += 16) {
            int ss[16]; float ww[16]; uint2 pp[16];
#pragma unroll
            for (int t = 0; t < 16; ++t) {
                ss[t] = __shfl(sreg, j + t);
                ww[t] = __shfl(wreg, j + t);
            }
#pragma unroll
            for (int t = 0; t < 16; ++t)
                pp[t] = *(const uint2*)(hq + (size_t)ss[t] * C_HID + lane * 8);
#pragma unroll
            for (int t = 0; t < 16; ++t) accum8i(acc, pp[t], ww[t]);
        }
        for (; j + 8 <= cnt; j += 8) {
            int ss[8]; float ww[8]; uint2 pp[8];
#pragma unroll
            for (int t = 0; t < 8; ++t) {
                ss[t] = __shfl(sreg, j + t);
                ww[t] = __shfl(wreg, j + t);
            }
#pragma unroll
            for (int t = 0; t < 8; ++t)
                pp[t] = *(const uint2*)(hq + (size_t)ss[t] * C_HID + lane * 8);
#pragma unroll
            for (int t = 0; t < 8; ++t) accum8i(acc, pp[t], ww[t]);
        }
        for (; j + 4 <= cnt; j += 4) {
            int ss[4]; float ww[4]; uint2 pp[4];
#pragma unroll
            for (int t = 0; t < 4; ++t) {
                ss[t] = __shfl(sreg, j + t);
                ww[t] = __shfl(wreg, j + t);
            }
#pragma unroll
            for (int t = 0; t < 4; ++t)
                pp[t] = *(const uint2*)(hq + (size_t)ss[t] * C_HID + lane * 8);
#pragma unroll
            for (int t = 0; t < 4; ++t) accum8i(acc, pp[t], ww[t]);
        }
        for (; j < cnt; ++j) {
            int sj = __shfl(sreg, j);
            float wj = __shfl(wreg, j);
            uint2 pj = *(const uint2*)(hq + (size_t)sj * C_HID + lane * 8);
            accum8i(acc, pj, wj);
        }
    }

    float4 ba = *(const float4*)(b1f + lane * 8);
    float4 bb = *(const float4*)(b1f + lane * 8 + 4);
    float r0 = fmaxf(acc[0] + ba.x, 0.f), r1 = fmaxf(acc[1] + ba.y, 0.f);
    float r2 = fmaxf(acc[2] + ba.z, 0.f), r3 = fmaxf(acc[3] + ba.w, 0.f);
    float r4 = fmaxf(acc[4] + bb.x, 0.f), r5 = fmaxf(acc[5] + bb.y, 0.f);
    float r6 = fmaxf(acc[6] + bb.z, 0.f), r7 = fmaxf(acc[7] + bb.w, 0.f);
    u32x4 o;
    o.x = (u32)f2bf(r0) | ((u32)f2bf(r1) << 16);
    o.y = (u32)f2bf(r2) | ((u32)f2bf(r3) << 16);
    o.z = (u32)f2bf(r4) | ((u32)f2bf(r5) << 16);
    o.w = (u32)f2bf(r6) | ((u32)f2bf(r7) << 16);
    // nontemporal: don't let the 50MB output stream evict h from L2
    __builtin_nontemporal_store(o, (u32x4*)(out + (size_t)v * C_HID + lane * 8));
}

// ---------------- agg2 + bias + log_softmax: bf16 h2, 24 edges in flight ----------------
__global__ __launch_bounds__(256) void k_agg2(
    const u16* __restrict__ h2, const int* __restrict__ csr, const int* __restrict__ offs,
    const float* __restrict__ dinv, const float* __restrict__ b2f,
    const int* __restrict__ flags, void* __restrict__ out, int n, int Etot) {
    int wave = threadIdx.x >> 6, lane = threadIdx.x & 63;
    int v = blockIdx.x * 4 + wave;
    if (v >= n) return;
    float dv = dinv[v];

    int g = lane / 10;            // 0..6
    int f4 = lane - g * 10;       // 0..9
    bool active = (g < 6);

    float4 acc = make_float4(0.f, 0.f, 0.f, 0.f);
    if (g == 0) {
        uint2 pv = *(const uint2*)(h2 + (size_t)v * C_OUT + f4 * 4);
        float w = dv * dv;
        acc.x = w * bf2f((u16)pv.x); acc.y = w * bf2f((u16)(pv.x >> 16));
        acc.z = w * bf2f((u16)pv.y); acc.w = w * bf2f((u16)(pv.y >> 16));
    }

    int e0 = imax(0, imin(offs[v], Etot));
    int e1 = imax(e0, imin(offs[v + 1], Etot));
    for (int base = e0; base < e1; base += 64) {
        int cnt = imin(64, e1 - base);
        int sreg = 0; float wreg = 0.f;
        if (lane < cnt) {
            u32 s = (u32)csr[base + lane];
            s = (s < (u32)n) ? s : 0u;
            sreg = (int)s;
            wreg = dv * dinv[s];
        }
        for (int j = 0; j < cnt; j += 24) {
            uint2 p[4]; float w4[4];
#pragma unroll
            for (int t = 0; t < 4; ++t) {
                int jj = j + t * 6 + g;
                int idx = imin(jj, cnt - 1);
                int sj = __shfl(sreg, idx);
                float wj = __shfl(wreg, idx);
                w4[t] = (active && jj < cnt) ? wj : 0.f;
                p[t] = make_uint2(0, 0);
                if (active) p[t] = *(const uint2*)(h2 + (size_t)sj * C_OUT + f4 * 4);
            }
#pragma unroll
            for (int t = 0; t < 4; ++t) {
                acc.x += w4[t] * bf2f((u16)p[t].x);
                acc.y += w4[t] * bf2f((u16)(p[t].x >> 16));
                acc.z += w4[t] * bf2f((u16)p[t].y);
                acc.w += w4[t] * bf2f((u16)(p[t].y >> 16));
            }
        }
    }

    float4 t;
    t.x = __shfl(acc.x, lane + 30); t.y = __shfl(acc.y, lane + 30);
    t.z = __shfl(acc.z, lane + 30); t.w = __shfl(acc.w, lane + 30);
    if (lane < 30) { acc.x += t.x; acc.y += t.y; acc.z += t.z; acc.w += t.w; }
    float4 t1, t2;
    t1.x = __shfl(acc.x, lane + 10); t1.y = __shfl(acc.y, lane + 10);
    t1.z = __shfl(acc.z, lane + 10); t1.w = __shfl(acc.w, lane + 10);
    t2.x = __shfl(acc.x, lane + 20); t2.y = __shfl(acc.y, lane + 20);
    t2.z = __shfl(acc.z, lane + 20); t2.w = __shfl(acc.w, lane + 20);
    if (lane < 10) {
        acc.x += t1.x + t2.x; acc.y += t1.y + t2.y;
        acc.z += t1.z + t2.z; acc.w += t1.w + t2.w;
        acc.x += b2f[f4 * 4 + 0]; acc.y += b2f[f4 * 4 + 1];
        acc.z += b2f[f4 * 4 + 2]; acc.w += b2f[f4 * 4 + 3];
    }

    float m = -1e30f;
    if (lane < 10) m = fmaxf(fmaxf(acc.x, acc.y), fmaxf(acc.z, acc.w));
    for (int off = 32; off > 0; off >>= 1) m = fmaxf(m, __shfl_xor(m, off));
    float s = 0.f;
    if (lane < 10)
        s = expf(acc.x - m) + expf(acc.y - m) + expf(acc.z - m) + expf(acc.w - m);
    for (int off = 32; off > 0; off >>= 1) s += __shfl_xor(s, off);
    if (lane < 10) {
        float ls = m + logf(s);
        if (flags[1]) {
            ushort4 o;
            o.x = f2bf(acc.x - ls); o.y = f2bf(acc.y - ls);
            o.z = f2bf(acc.z - ls); o.w = f2bf(acc.w - ls);
            *(ushort4*)((u16*)out + (size_t)v * C_OUT + f4 * 4) = o;
        } else {
            float4 o = make_float4(acc.x - ls, acc.y - ls, acc.z - ls, acc.w - ls);
            *(float4*)((float*)out + (size_t)v * C_OUT + f4 * 4) = o;
        }
    }
}

// ---------------- launch ----------------

extern "C" void kernel_launch(void* const* d_in, const int* in_sizes, int n_in,
                              void* d_out, int out_size, void* d_ws, size_t ws_size,
                              hipStream_t stream) {
    const void* x = d_in[0];
    const int* ei = (const int*)d_in[1];
    const void* W1 = d_in[2];
    const void* b1 = d_in[3];
    const void* W2 = d_in[4];
    const void* b2 = d_in[5];

    const int N = out_size / C_OUT;
    const int Mx = in_sizes[0] / C_IN;
    const int M = (N < Mx) ? N : Mx;
    const int ECAP = in_sizes[1];
    const int E = ECAP / 2;

    char* p = (char*)d_ws;
    size_t used = 0;
    auto carve = [&](size_t bytes) -> void* {
        void* r = (void*)p;
        size_t b = (bytes + 255) & ~(size_t)255;
        p += b; used += b;
        return r;
    };
    int* flags = (int*)carve(256);
    int* deg = (int*)carve((size_t)N * 4);
    int* cursor = (int*)carve((size_t)N * 4);
    float* dinv = (float*)carve((size_t)N * 4);
    int* offs = (int*)carve((size_t)(N + 1) * 4);
    int* bsum = (int*)carve(8192);
    int* csr = (int*)carve((size_t)E * 4);
    u16* w1t = (u16*)carve((size_t)C_HID * C_IN * 2);
    u16* w2t = (u16*)carve((size_t)64 * C_HID * 2);
    float* b1f = (float*)carve(C_HID * 4);
    float* b2f = (float*)carve(256);
    u16* bufA = (u16*)carve((size_t)N * C_HID * 2);   // hagg
    u16* bufB = (u16*)carve((size_t)N * C_HID * 2);   // h_i8, then h2 (bf16)
    if (used > ws_size) return;

    char* h_i8 = (char*)bufB;
    u16* hagg = bufA;
    u16* h2 = bufB;

    const int NB = (N + 255) / 256;
    const int EB = (E + 255) / 256;

    k_init<<<NB, 256, 0, stream>>>((const u32*)x, ei, flags, deg, cursor, N);
    k_deg<<<EB, 256, 0, stream>>>(ei, flags, deg, E, ECAP, N);
    k_scanA<<<NB, 256, 0, stream>>>(deg, bsum, dinv, N);
    k_scanB<<<1, 256, 0, stream>>>(bsum, NB, offs, N);
    k_scanC<<<NB, 256, 0, stream>>>(deg, bsum, offs, N);
    k_sort<<<EB, 256, 0, stream>>>(ei, flags, offs, cursor, csr, E, ECAP, N);

    k_prep<<<256, 256, 0, stream>>>(W1, b1, W2, b2, flags, w1t, w2t, b1f, b2f);

    int nbx = (M + 63) / 64;
    k_gemm128<<<nbx * 4, 256, 0, stream>>>((const u16*)x, (const float*)x, flags,
                                           w1t, h_i8, M, C_IN, C_HID);

    k_agg1<<<(N + 3) / 4, 256, 0, stream>>>(h_i8, csr, offs, dinv, b1f, hagg, N, E);

    dim3 g2((N + 63) / 64, 1);
    k_gemm64<<<g2, 256, 0, stream>>>(hagg, w2t, h2, N, C_HID, C_OUT, C_OUT);

    k_agg2<<<(N + 3) / 4, 256, 0, stream>>>(h2, csr, offs, dinv, b2f, flags, d_out, N, E);
}

// Round 10
// 404.531 us; speedup vs baseline: 1.3136x; 1.3136x over previous
//
#include <hip/hip_runtime.h>

// GCN 2-layer forward on gfx950.
// R20: gemm128 reverted to R16 (75us known; LDS-free attempts R18/R19 dead:
//      compiler sinks prefetches without a barrier skeleton, VGPR stays ~50).
//      New: k_gemm64 restructured - w2t staged to LDS once (48KB, 1 barrier),
//      A streamed barrier-free with direct-reg fragments (stream-bound, so
//      the R18 serialization trap doesn't apply). k_prep W1 transpose now
//      64x64 LDS-tiled (was stride-2KB scalar reads, 16x overfetch).
//      Rest = R16: int8 h, bf16 h2, nt-store hagg, XCD remap.

typedef unsigned int u32;
typedef unsigned short u16;
typedef __bf16 bf16x8 __attribute__((ext_vector_type(8)));
typedef float f32x4 __attribute__((ext_vector_type(4)));
typedef u32 u32x4 __attribute__((ext_vector_type(4)));

#define C_IN 512
#define C_HID 512
#define C_OUT 40
#define H_SCALE 24.0f
#define H_INV_SCALE (1.0f / 24.0f)

__device__ __forceinline__ float bf2f(u16 u) {
    u32 x = ((u32)u) << 16;
    return __builtin_bit_cast(float, x);
}
__device__ __forceinline__ u16 f2bf(float f) {
    u32 x = __builtin_bit_cast(u32, f);
    x += 0x7fffu + ((x >> 16) & 1u);   // RNE
    return (u16)(x >> 16);
}
__device__ __forceinline__ char q8(float v) {
    float c = fminf(fmaxf(v * H_SCALE, -127.f), 127.f);
    return (char)__float2int_rn(c);
}
__device__ __forceinline__ u32 pk2(float a, float b) {
    u16 lo = __builtin_bit_cast(u16, (__bf16)a);
    u16 hi = __builtin_bit_cast(u16, (__bf16)b);
    return (u32)lo | ((u32)hi << 16);
}
__device__ __forceinline__ u32x4 pk8(float4 a, float4 b) {
    u32x4 r;
    r.x = pk2(a.x, a.y); r.y = pk2(a.z, a.w);
    r.z = pk2(b.x, b.y); r.w = pk2(b.z, b.w);
    return r;
}
__host__ __device__ __forceinline__ int imin(int a, int b) { return a < b ? a : b; }
__host__ __device__ __forceinline__ int imax(int a, int b) { return a > b ? a : b; }

// ---------------- init + dtype detect (fused) ----------------
__global__ void k_init(const u32* __restrict__ x32, const int* __restrict__ ei,
                       int* flags, int* deg, int* cursor, int n) {
    if (blockIdx.x == 0 && threadIdx.x < 64) {
        int lane = threadIdx.x;
        int z = (ei[2 * lane + 1] == 0) ? 1 : 0;
        u32 e = (x32[lane] >> 7) & 0xff;
        int v = (e >= 110 && e <= 133) ? 1 : 0;
        unsigned long long bz = __ballot(z);
        unsigned long long bv = __ballot(v);
        if (lane == 0) {
            flags[0] = (__popcll(bz) == 64) ? 2 : 1;   // int32 step per element
            flags[1] = (__popcll(bv) >= 48) ? 1 : 0;   // floats bf16-packed?
        }
    }
    int i = blockIdx.x * 256 + threadIdx.x;
    if (i < n) { deg[i] = 1; cursor[i] = 0; }          // self-loop
}

__global__ void k_deg(const int* __restrict__ ei, const int* __restrict__ flags,
                      int* deg, int E, int ecap, int n) {
    int e = blockIdx.x * 256 + threadIdx.x;
    if (e >= E) return;
    int st = flags[0];
    int cap = ecap * st - 1;
    u32 d = (u32)ei[imin((E + e) * st, cap)];
    if (d < (u32)n) atomicAdd(&deg[d], 1);
}

// block sums of (deg-1) + dinv (fused)
__global__ void k_scanA(const int* __restrict__ deg, int* bsum, float* dinv, int n) {
    __shared__ int sh[256];
    int i = blockIdx.x * 256 + threadIdx.x;
    int dv = (i < n) ? deg[i] : 1;
    if (i < n) dinv[i] = rsqrtf((float)imax(dv, 1));
    sh[threadIdx.x] = (i < n) ? dv - 1 : 0;
    __syncthreads();
    for (int d = 128; d > 0; d >>= 1) {
        if (threadIdx.x < d) sh[threadIdx.x] += sh[threadIdx.x + d];
        __syncthreads();
    }
    if (threadIdx.x == 0) bsum[blockIdx.x] = sh[0];
}

// parallel exclusive scan of bsum (one 256-thread block, chunked with carry)
__global__ void k_scanB(int* bsum, int nb, int* offs, int n) {
    __shared__ int sh[256];
    int t = threadIdx.x;
    int carry = 0;
    for (int base = 0; base < nb; base += 256) {
        int i = base + t;
        int v = (i < nb) ? bsum[i] : 0;
        sh[t] = v;
        __syncthreads();
        for (int d = 1; d < 256; d <<= 1) {
            int add = (t >= d) ? sh[t - d] : 0;
            __syncthreads();
            sh[t] += add;
            __syncthreads();
        }
        if (i < nb) bsum[i] = carry + sh[t] - v;   // exclusive
        int tot = sh[255];
        __syncthreads();
        carry += tot;
    }
    if (t == 0) offs[n] = carry;
}

__global__ void k_scanC(const int* __restrict__ deg, const int* __restrict__ bsum,
                        int* offs, int n) {
    __shared__ int sh[256];
    int t = threadIdx.x;
    int i = blockIdx.x * 256 + t;
    int v = (i < n) ? deg[i] - 1 : 0;
    sh[t] = v;
    __syncthreads();
    for (int d = 1; d < 256; d <<= 1) {
        int add = (t >= d) ? sh[t - d] : 0;
        __syncthreads();
        sh[t] += add;
        __syncthreads();
    }
    if (i < n) offs[i] = bsum[blockIdx.x] + sh[t] - v;
}

__global__ void k_sort(const int* __restrict__ ei, const int* __restrict__ flags,
                       const int* __restrict__ offs, int* cursor, int* csr,
                       int E, int ecap, int n) {
    int e = blockIdx.x * 256 + threadIdx.x;
    if (e >= E) return;
    int st = flags[0];
    int cap = ecap * st - 1;
    u32 d = (u32)ei[imin((E + e) * st, cap)];
    u32 s = (u32)ei[imin(e * st, cap)];
    if (d < (u32)n && s < (u32)n) {
        int pos = offs[d] + atomicAdd(&cursor[(int)d], 1);
        if ((u32)pos < (u32)E) csr[pos] = (int)s;
    }
}

// ---------------- prep: tiled W1 transpose + w2t + biases ----------------
__device__ __forceinline__ float ldf(const void* p, int i, int isbf) {
    return isbf ? bf2f(((const u16*)p)[i]) : ((const float*)p)[i];
}

__global__ __launch_bounds__(256) void k_prep(
    const void* __restrict__ W1, const void* __restrict__ b1,
    const void* __restrict__ W2, const void* __restrict__ b2,
    const int* __restrict__ flags, u16* __restrict__ w1t, u16* __restrict__ w2t,
    float* __restrict__ b1f, float* __restrict__ b2f) {
    __shared__ float tile[64][65];
    int isbf = flags[1];
    int tid = threadIdx.x;
    int stride = gridDim.x * 256;
    int i0 = blockIdx.x * 256 + tid;
    // W1 transpose in 64x64 tiles: both read and write coalesced.
    for (int t = blockIdx.x; t < 64; t += gridDim.x) {
        int tr = t >> 3, tc = t & 7;          // k-tile, n-tile
        int rr = tid >> 2, cq = (tid & 3) * 16;
#pragma unroll
        for (int c = 0; c < 16; ++c)
            tile[cq + c][rr] = ldf(W1, (tr * 64 + rr) * 512 + tc * 64 + cq + c, isbf);
        __syncthreads();
#pragma unroll
        for (int c = 0; c < 16; ++c)
            w1t[(size_t)(tc * 64 + rr) * 512 + tr * 64 + cq + c] = f2bf(tile[rr][cq + c]);
        __syncthreads();
    }
    for (int i = i0; i < 64 * 512; i += stride) {
        int n = i >> 9, k = i & 511;
        w2t[i] = (n < C_OUT) ? f2bf(ldf(W2, k * C_OUT + n, isbf)) : (u16)0;
    }
    if (i0 < C_HID) b1f[i0] = ldf(b1, i0, isbf);
    if (i0 < C_OUT) b2f[i0] = ldf(b2, i0, isbf);
}

// ---------------- GEMM1: 64x128 tile, BK=64, split-half LDS (R16) -----------
typedef __attribute__((address_space(1))) const u32 glds_src;
typedef __attribute__((address_space(3))) u32 glds_dst;

__global__ __launch_bounds__(256) void k_gemm128(
    const u16* __restrict__ xbf, const float* __restrict__ xf32,
    const int* __restrict__ flags, const u16* __restrict__ Bt,
    char* __restrict__ C, int M, int K, int ldc) {
    int isbf = flags[1];
    __shared__ __align__(16) u16 As0[64 * 32], As1[64 * 32];
    __shared__ __align__(16) u16 Bs0[128 * 32], Bs1[128 * 32];
    int tid = threadIdx.x;
    int wave = tid >> 6, lane = tid & 63;
    int quad = lane >> 4, lrow = lane & 15;
    int wrow = (wave & 1) * 32, wcol = (wave >> 1) * 64;

    int nwg = gridDim.x;
    int id = blockIdx.x;
    int q = nwg >> 3, r = nwg & 7;
    int xcd = id & 7, j8 = id >> 3;
    int wg = (xcd < r ? xcd * (q + 1) : r * (q + 1) + (xcd - r) * q) + j8;
    int row0 = (wg >> 2) * 64;
    int n0 = (wg & 3) * 128;

    int lr = lane >> 2;
    int lc = (lane & 3) * 8;
    int ar = row0 + wave * 16 + lr;
    int br = n0 + wave * 32 + lr;
    u16* As0_w = As0 + (wave * 16) * 32;
    u16* As1_w = As1 + (wave * 16) * 32;
    u16* Bs0_w = Bs0 + (wave * 32) * 32;
    u16* Bs1_w = Bs1 + (wave * 32) * 32;

    f32x4 acc[2][4] = {};
    int kTiles = K >> 6;   // BK=64
    for (int kt = 0; kt < kTiles; ++kt) {
        int k0 = kt * 64;
        int a0 = imin(ar, M - 1);
        if (isbf) {
            const u16* gA0 = xbf + (size_t)a0 * K + k0 + lc;
            __builtin_amdgcn_global_load_lds((glds_src*)gA0, (glds_dst*)As0_w, 16, 0, 0);
            __builtin_amdgcn_global_load_lds((glds_src*)(gA0 + 32), (glds_dst*)As1_w, 16, 0, 0);
        } else {
            const float* f0 = xf32 + (size_t)a0 * K + k0 + lc;
            float4 u0 = *(const float4*)(f0);
            float4 u1 = *(const float4*)(f0 + 4);
            float4 u2 = *(const float4*)(f0 + 32);
            float4 u3 = *(const float4*)(f0 + 36);
            *(u32x4*)(As0_w + lr * 32 + lc) = pk8(u0, u1);
            *(u32x4*)(As1_w + lr * 32 + lc) = pk8(u2, u3);
        }
        const u16* gB0 = Bt + (size_t)br * K + k0 + lc;
        const u16* gB1 = Bt + (size_t)(br + 16) * K + k0 + lc;
        __builtin_amdgcn_global_load_lds((glds_src*)gB0, (glds_dst*)Bs0_w, 16, 0, 0);
        __builtin_amdgcn_global_load_lds((glds_src*)gB1, (glds_dst*)(Bs0_w + 16 * 32), 16, 0, 0);
        __builtin_amdgcn_global_load_lds((glds_src*)(gB0 + 32), (glds_dst*)Bs1_w, 16, 0, 0);
        __builtin_amdgcn_global_load_lds((glds_src*)(gB1 + 32), (glds_dst*)(Bs1_w + 16 * 32), 16, 0, 0);
        __syncthreads();
#pragma unroll
        for (int ko = 0; ko < 2; ++ko) {
            const u16* Asrc = ko ? As1 : As0;
            const u16* Bsrc = ko ? Bs1 : Bs0;
            bf16x8 af[2], bfr[4];
#pragma unroll
            for (int i = 0; i < 2; ++i)
                af[i] = *(const bf16x8*)(Asrc + (wrow + i * 16 + lrow) * 32 + quad * 8);
#pragma unroll
            for (int j = 0; j < 4; ++j)
                bfr[j] = *(const bf16x8*)(Bsrc + (wcol + j * 16 + lrow) * 32 + quad * 8);
#pragma unroll
            for (int i = 0; i < 2; ++i)
#pragma unroll
                for (int j = 0; j < 4; ++j)
                    acc[i][j] = __builtin_amdgcn_mfma_f32_16x16x32_bf16(af[i], bfr[j],
                                                                        acc[i][j], 0, 0, 0);
        }
        __syncthreads();
    }
#pragma unroll
    for (int i = 0; i < 2; ++i)
#pragma unroll
        for (int j = 0; j < 4; ++j)
#pragma unroll
            for (int r2 = 0; r2 < 4; ++r2) {
                int row = row0 + wrow + i * 16 + quad * 4 + r2;
                int col = n0 + wcol + j * 16 + lrow;
                if (row < M) C[(size_t)row * ldc + col] = q8(acc[i][j][r2]);
            }
}

// ---------------- GEMM2: w2t-in-LDS, barrier-free A stream, bf16 out --------
// Block: 128 rows (4 waves x 32). w2t rows 0..47 staged once into LDS
// ([48][520] u16: row stride 1040B -> 2-way bank alias on reads = free).
// Per wave, per k-step: 2 A-frags direct from global (coalesced 16B/lane),
// 3 B-frags from LDS, 6 MFMA. No barriers in the loop; stream-bound.
#define B2ROW 520
__global__ __launch_bounds__(256) void k_gemm64(
    const u16* __restrict__ A, const u16* __restrict__ Bt, u16* __restrict__ Cout,
    int M, int K, int Ncols, int ldc) {
    __shared__ __align__(16) u16 Bsh[48 * B2ROW];
    int tid = threadIdx.x;
    int wave = tid >> 6, lane = tid & 63;
    int quad = lane >> 4, lrow = lane & 15;

    for (int i = tid; i < 48 * 64; i += 256) {
        int rw = i >> 6, cv = (i & 63) * 8;
        *(uint4*)(Bsh + rw * B2ROW + cv) = *(const uint4*)(Bt + (size_t)rw * 512 + cv);
    }
    __syncthreads();

    int row0 = blockIdx.x * 128 + wave * 32;
    int r0 = imin(row0 + lrow, M - 1);
    int r1 = imin(row0 + 16 + lrow, M - 1);
    const u16* a0p = A + (size_t)r0 * K + quad * 8;
    const u16* a1p = A + (size_t)r1 * K + quad * 8;
    const u16* b0p = Bsh + (0 * 16 + lrow) * B2ROW + quad * 8;
    const u16* b1p = Bsh + (1 * 16 + lrow) * B2ROW + quad * 8;
    const u16* b2p = Bsh + (2 * 16 + lrow) * B2ROW + quad * 8;

    f32x4 c00 = {}, c01 = {}, c02 = {};
    f32x4 c10 = {}, c11 = {}, c12 = {};
#pragma unroll 4
    for (int k0 = 0; k0 < C_HID; k0 += 32) {
        bf16x8 a0 = *(const bf16x8*)(a0p + k0);
        bf16x8 a1 = *(const bf16x8*)(a1p + k0);
        bf16x8 b0 = *(const bf16x8*)(b0p + k0);
        bf16x8 b1 = *(const bf16x8*)(b1p + k0);
        bf16x8 b2 = *(const bf16x8*)(b2p + k0);
        c00 = __builtin_amdgcn_mfma_f32_16x16x32_bf16(a0, b0, c00, 0, 0, 0);
        c01 = __builtin_amdgcn_mfma_f32_16x16x32_bf16(a0, b1, c01, 0, 0, 0);
        c02 = __builtin_amdgcn_mfma_f32_16x16x32_bf16(a0, b2, c02, 0, 0, 0);
        c10 = __builtin_amdgcn_mfma_f32_16x16x32_bf16(a1, b0, c10, 0, 0, 0);
        c11 = __builtin_amdgcn_mfma_f32_16x16x32_bf16(a1, b1, c11, 0, 0, 0);
        c12 = __builtin_amdgcn_mfma_f32_16x16x32_bf16(a1, b2, c12, 0, 0, 0);
    }
    f32x4 cc[2][3] = {{c00, c01, c02}, {c10, c11, c12}};
#pragma unroll
    for (int i = 0; i < 2; ++i)
#pragma unroll
        for (int t = 0; t < 3; ++t)
#pragma unroll
            for (int r = 0; r < 4; ++r) {
                int row = row0 + i * 16 + quad * 4 + r;
                int col = t * 16 + lrow;
                if (row < M && col < Ncols)
                    Cout[(size_t)row * ldc + col] = f2bf(cc[i][t][r]);
            }
}

// ---------------- agg1: hagg = ReLU(Anorm*h + b1), int8 in, bf16 out ----------------
__device__ __forceinline__ void accum8i(float* acc, uint2 p, float w) {
    int lo = (int)p.x, hi = (int)p.y;
    acc[0] += w * (float)(signed char)(lo);
    acc[1] += w * (float)(signed char)(lo >> 8);
    acc[2] += w * (float)(signed char)(lo >> 16);
    acc[3] += w * (float)(signed char)(lo >> 24);
    acc[4] += w * (float)(signed char)(hi);
    acc[5] += w * (float)(signed char)(hi >> 8);
    acc[6] += w * (float)(signed char)(hi >> 16);
    acc[7] += w * (float)(signed char)(hi >> 24);
}

__global__ __launch_bounds__(256) void k_agg1(
    const char* __restrict__ hq, const int* __restrict__ csr, const int* __restrict__ offs,
    const float* __restrict__ dinv, const float* __restrict__ b1f,
    u16* __restrict__ out, int n, int Etot) {
    int wave = threadIdx.x >> 6, lane = threadIdx.x & 63;
    int v = blockIdx.x * 4 + wave;
    if (v >= n) return;
    float dv = dinv[v];
    float wself = dv * dv * H_INV_SCALE;

    float acc[8] = {0.f, 0.f, 0.f, 0.f, 0.f, 0.f, 0.f, 0.f};
    uint2 hs = *(const uint2*)(hq + (size_t)v * C_HID + lane * 8);
    accum8i(acc, hs, wself);

    int e0 = imax(0, imin(offs[v], Etot));
    int e1 = imax(e0, imin(offs[v + 1], Etot));
    for (int base = e0; base < e1; base += 64) {
        int cnt = imin(64, e1 - base);
        int sreg = 0; float wreg = 0.f;
        if (lane < cnt) {
            u32 s = (u32)csr[base + lane];
            s = (s < (u32)n) ? s : 0u;
            sreg = (int)s;
            wreg = dv * dinv[s] * H_INV_SCALE;
        }
        int j = 0;
        for (; j + 16 <= cnt; j += 16) {
            int ss[16]; float ww[16]; uint2 pp[16];
#pragma unroll
            for (int t = 0; t < 16; ++t) {
                ss[t] = __shfl(sreg, j + t);
                ww[t] = __shfl(wreg, j + t);
            }
#pragma unroll
            for (int t = 0; t < 16; ++t)
                pp[t] = *(const uint2*)(hq + (size_t)ss[t] * C_HID + lane * 8);
#pragma unroll
            for (int t = 0; t < 16; ++t) accum8i(acc, pp[t], ww[t]);
        }
        for (; j + 8 <= cnt; j += 8) {
            int ss[8]; float ww[8]; uint2 pp[8];
#pragma unroll
            for (int t = 0; t < 8; ++t) {
                ss[t] = __shfl(sreg, j + t);
                ww[t] = __shfl(wreg, j + t);
            }
#pragma unroll
            for (int t = 0; t < 8; ++t)
                pp[t] = *(const uint2*)(hq + (size_t)ss[t] * C_HID + lane * 8);
#pragma unroll
            for (int t = 0; t < 8; ++t) accum8i(acc, pp[t], ww[t]);
        }
        for (; j + 4 <= cnt; j += 4) {
            int ss[4]; float ww[4]; uint2 pp[4];
#pragma unroll
            for (int t = 0; t < 4; ++t) {
                ss[t] = __shfl(sreg, j + t);
                ww[t] = __shfl(wreg, j + t);
            }
#pragma unroll
            for (int t = 0; t < 4; ++t)
                pp[t] = *(const uint2*)(hq + (size_t)ss[t] * C_HID + lane * 8);
#pragma unroll
            for (int t = 0; t < 4; ++t) accum8i(acc, pp[t], ww[t]);
        }
        for (; j < cnt; ++j) {
            int sj = __shfl(sreg, j);
            float wj = __shfl(wreg, j);
            uint2 pj = *(const uint2*)(hq + (size_t)sj * C_HID + lane * 8);
            accum8i(acc, pj, wj);
        }
    }

    float4 ba = *(const float4*)(b1f + lane * 8);
    float4 bb = *(const float4*)(b1f + lane * 8 + 4);
    float r0 = fmaxf(acc[0] + ba.x, 0.f), r1 = fmaxf(acc[1] + ba.y, 0.f);
    float r2 = fmaxf(acc[2] + ba.z, 0.f), r3 = fmaxf(acc[3] + ba.w, 0.f);
    float r4 = fmaxf(acc[4] + bb.x, 0.f), r5 = fmaxf(acc[5] + bb.y, 0.f);
    float r6 = fmaxf(acc[6] + bb.z, 0.f), r7 = fmaxf(acc[7] + bb.w, 0.f);
    u32x4 o;
    o.x = (u32)f2bf(r0) | ((u32)f2bf(r1) << 16);
    o.y = (u32)f2bf(r2) | ((u32)f2bf(r3) << 16);
    o.z = (u32)f2bf(r4) | ((u32)f2bf(r5) << 16);
    o.w = (u32)f2bf(r6) | ((u32)f2bf(r7) << 16);
    // nontemporal: don't let the 50MB output stream evict h from L2
    __builtin_nontemporal_store(o, (u32x4*)(out + (size_t)v * C_HID + lane * 8));
}

// ---------------- agg2 + bias + log_softmax: bf16 h2, 24 edges in flight ----------------
__global__ __launch_bounds__(256) void k_agg2(
    const u16* __restrict__ h2, const int* __restrict__ csr, const int* __restrict__ offs,
    const float* __restrict__ dinv, const float* __restrict__ b2f,
    const int* __restrict__ flags, void* __restrict__ out, int n, int Etot) {
    int wave = threadIdx.x >> 6, lane = threadIdx.x & 63;
    int v = blockIdx.x * 4 + wave;
    if (v >= n) return;
    float dv = dinv[v];

    int g = lane / 10;            // 0..6
    int f4 = lane - g * 10;       // 0..9
    bool active = (g < 6);

    float4 acc = make_float4(0.f, 0.f, 0.f, 0.f);
    if (g == 0) {
        uint2 pv = *(const uint2*)(h2 + (size_t)v * C_OUT + f4 * 4);
        float w = dv * dv;
        acc.x = w * bf2f((u16)pv.x); acc.y = w * bf2f((u16)(pv.x >> 16));
        acc.z = w * bf2f((u16)pv.y); acc.w = w * bf2f((u16)(pv.y >> 16));
    }

    int e0 = imax(0, imin(offs[v], Etot));
    int e1 = imax(e0, imin(offs[v + 1], Etot));
    for (int base = e0; base < e1; base += 64) {
        int cnt = imin(64, e1 - base);
        int sreg = 0; float wreg = 0.f;
        if (lane < cnt) {
            u32 s = (u32)csr[base + lane];
            s = (s < (u32)n) ? s : 0u;
            sreg = (int)s;
            wreg = dv * dinv[s];
        }
        for (int j = 0; j < cnt; j += 24) {
            uint2 p[4]; float w4[4];
#pragma unroll
            for (int t = 0; t < 4; ++t) {
                int jj = j + t * 6 + g;
                int idx = imin(jj, cnt - 1);
                int sj = __shfl(sreg, idx);
                float wj = __shfl(wreg, idx);
                w4[t] = (active && jj < cnt) ? wj : 0.f;
                p[t] = make_uint2(0, 0);
                if (active) p[t] = *(const uint2*)(h2 + (size_t)sj * C_OUT + f4 * 4);
            }
#pragma unroll
            for (int t = 0; t < 4; ++t) {
                acc.x += w4[t] * bf2f((u16)p[t].x);
                acc.y += w4[t] * bf2f((u16)(p[t].x >> 16));
                acc.z += w4[t] * bf2f((u16)p[t].y);
                acc.w += w4[t] * bf2f((u16)(p[t].y >> 16));
            }
        }
    }

    float4 t;
    t.x = __shfl(acc.x, lane + 30); t.y = __shfl(acc.y, lane + 30);
    t.z = __shfl(acc.z, lane + 30); t.w = __shfl(acc.w, lane + 30);
    if (lane < 30) { acc.x += t.x; acc.y += t.y; acc.z += t.z; acc.w += t.w; }
    float4 t1, t2;
    t1.x = __shfl(acc.x, lane + 10); t1.y = __shfl(acc.y, lane + 10);
    t1.z = __shfl(acc.z, lane + 10); t1.w = __shfl(acc.w, lane + 10);
    t2.x = __shfl(acc.x, lane + 20); t2.y = __shfl(acc.y, lane + 20);
    t2.z = __shfl(acc.z, lane + 20); t2.w = __shfl(acc.w, lane + 20);
    if (lane < 10) {
        acc.x += t1.x + t2.x; acc.y += t1.y + t2.y;
        acc.z += t1.z + t2.z; acc.w += t1.w + t2.w;
        acc.x += b2f[f4 * 4 + 0]; acc.y += b2f[f4 * 4 + 1];
        acc.z += b2f[f4 * 4 + 2]; acc.w += b2f[f4 * 4 + 3];
    }

    float m = -1e30f;
    if (lane < 10) m = fmaxf(fmaxf(acc.x, acc.y), fmaxf(acc.z, acc.w));
    for (int off = 32; off > 0; off >>= 1) m = fmaxf(m, __shfl_xor(m, off));
    float s = 0.f;
    if (lane < 10)
        s = expf(acc.x - m) + expf(acc.y - m) + expf(acc.z - m) + expf(acc.w - m);
    for (int off = 32; off > 0; off >>= 1) s += __shfl_xor(s, off);
    if (lane < 10) {
        float ls = m + logf(s);
        if (flags[1]) {
            ushort4 o;
            o.x = f2bf(acc.x - ls); o.y = f2bf(acc.y - ls);
            o.z = f2bf(acc.z - ls); o.w = f2bf(acc.w - ls);
            *(ushort4*)((u16*)out + (size_t)v * C_OUT + f4 * 4) = o;
        } else {
            float4 o = make_float4(acc.x - ls, acc.y - ls, acc.z - ls, acc.w - ls);
            *(float4*)((float*)out + (size_t)v * C_OUT + f4 * 4) = o;
        }
    }
}

// ---------------- launch ----------------

extern "C" void kernel_launch(void* const* d_in, const int* in_sizes, int n_in,
                              void* d_out, int out_size, void* d_ws, size_t ws_size,
                              hipStream_t stream) {
    const void* x = d_in[0];
    const int* ei = (const int*)d_in[1];
    const void* W1 = d_in[2];
    const void* b1 = d_in[3];
    const void* W2 = d_in[4];
    const void* b2 = d_in[5];

    const int N = out_size / C_OUT;
    const int Mx = in_sizes[0] / C_IN;
    const int M = (N < Mx) ? N : Mx;
    const int ECAP = in_sizes[1];
    const int E = ECAP / 2;

    char* p = (char*)d_ws;
    size_t used = 0;
    auto carve = [&](size_t bytes) -> void* {
        void* r = (void*)p;
        size_t b = (bytes + 255) & ~(size_t)255;
        p += b; used += b;
        return r;
    };
    int* flags = (int*)carve(256);
    int* deg = (int*)carve((size_t)N * 4);
    int* cursor = (int*)carve((size_t)N * 4);
    float* dinv = (float*)carve((size_t)N * 4);
    int* offs = (int*)carve((size_t)(N + 1) * 4);
    int* bsum = (int*)carve(8192);
    int* csr = (int*)carve((size_t)E * 4);
    u16* w1t = (u16*)carve((size_t)C_HID * C_IN * 2);
    u16* w2t = (u16*)carve((size_t)64 * C_HID * 2);
    float* b1f = (float*)carve(C_HID * 4);
    float* b2f = (float*)carve(256);
    u16* bufA = (u16*)carve((size_t)N * C_HID * 2);   // hagg
    u16* bufB = (u16*)carve((size_t)N * C_HID * 2);   // h_i8, then h2 (bf16)
    if (used > ws_size) return;

    char* h_i8 = (char*)bufB;
    u16* hagg = bufA;
    u16* h2 = bufB;

    const int NB = (N + 255) / 256;
    const int EB = (E + 255) / 256;

    k_init<<<NB, 256, 0, stream>>>((const u32*)x, ei, flags, deg, cursor, N);
    k_deg<<<EB, 256, 0, stream>>>(ei, flags, deg, E, ECAP, N);
    k_scanA<<<NB, 256, 0, stream>>>(deg, bsum, dinv, N);
    k_scanB<<<1, 256, 0, stream>>>(bsum, NB, offs, N);
    k_scanC<<<NB, 256, 0, stream>>>(deg, bsum, offs, N);
    k_sort<<<EB, 256, 0, stream>>>(ei, flags, offs, cursor, csr, E, ECAP, N);

    k_prep<<<256, 256, 0, stream>>>(W1, b1, W2, b2, flags, w1t, w2t, b1f, b2f);

    int nbx = (M + 63) / 64;
    k_gemm128<<<nbx * 4, 256, 0, stream>>>((const u16*)x, (const float*)x, flags,
                                           w1t, h_i8, M, C_IN, C_HID);

    k_agg1<<<(N + 3) / 4, 256, 0, stream>>>(h_i8, csr, offs, dinv, b1f, hagg, N, E);

    k_gemm64<<<(M + 127) / 128, 256, 0, stream>>>(hagg, w2t, h2, N, C_HID, C_OUT, C_OUT);

    k_agg2<<<(N + 3) / 4, 256, 0, stream>>>(h2, csr, offs, dinv, b2f, flags, d_out, N, E);
}

// Round 11
// 398.957 us; speedup vs baseline: 1.3319x; 1.0140x over previous
//
#include <hip/hip_runtime.h>

// GCN 2-layer forward on gfx950.
// R21: dispatch-count reduction (10 -> 8) targeting the ~260us of "dark"
//      time spread across small kernels:
//      - k_initprep: init + prep fused (flags computed block-locally);
//        also zeroes the scan lookback state.
//      - k_scan: scanA+scanB+scanC replaced by one decoupled-lookback scan
//        (196 chunks; one pass over deg instead of three).
//      gemm128 (R16, 76us), agg1 (int8, 67us), gemm64 (R20), agg2, deg,
//      sort unchanged.

typedef unsigned int u32;
typedef unsigned short u16;
typedef unsigned long long u64;
typedef __bf16 bf16x8 __attribute__((ext_vector_type(8)));
typedef float f32x4 __attribute__((ext_vector_type(4)));
typedef u32 u32x4 __attribute__((ext_vector_type(4)));

#define C_IN 512
#define C_HID 512
#define C_OUT 40
#define H_SCALE 24.0f
#define H_INV_SCALE (1.0f / 24.0f)

__device__ __forceinline__ float bf2f(u16 u) {
    u32 x = ((u32)u) << 16;
    return __builtin_bit_cast(float, x);
}
__device__ __forceinline__ u16 f2bf(float f) {
    u32 x = __builtin_bit_cast(u32, f);
    x += 0x7fffu + ((x >> 16) & 1u);   // RNE
    return (u16)(x >> 16);
}
__device__ __forceinline__ char q8(float v) {
    float c = fminf(fmaxf(v * H_SCALE, -127.f), 127.f);
    return (char)__float2int_rn(c);
}
__device__ __forceinline__ u32 pk2(float a, float b) {
    u16 lo = __builtin_bit_cast(u16, (__bf16)a);
    u16 hi = __builtin_bit_cast(u16, (__bf16)b);
    return (u32)lo | ((u32)hi << 16);
}
__device__ __forceinline__ u32x4 pk8(float4 a, float4 b) {
    u32x4 r;
    r.x = pk2(a.x, a.y); r.y = pk2(a.z, a.w);
    r.z = pk2(b.x, b.y); r.w = pk2(b.z, b.w);
    return r;
}
__host__ __device__ __forceinline__ int imin(int a, int b) { return a < b ? a : b; }
__host__ __device__ __forceinline__ int imax(int a, int b) { return a > b ? a : b; }

__device__ __forceinline__ float ldf(const void* p, int i, int isbf) {
    return isbf ? bf2f(((const u16*)p)[i]) : ((const float*)p)[i];
}

// ---------------- initprep: flags + deg/cursor/state init + weight prep -----
__global__ __launch_bounds__(256) void k_initprep(
    const u32* __restrict__ x32, const int* __restrict__ ei,
    const void* __restrict__ W1, const void* __restrict__ b1,
    const void* __restrict__ W2, const void* __restrict__ b2,
    int* flags, int* deg, int* cursor, u64* state,
    u16* __restrict__ w1t, u16* __restrict__ w2t,
    float* __restrict__ b1f, float* __restrict__ b2f,
    int n, int nchunks) {
    __shared__ float tile[64][65];
    __shared__ int s_flags[2];
    int tid = threadIdx.x;
    // block-local dtype detection (no cross-block dependency)
    if (tid < 64) {
        int lane = tid;
        int z = (ei[2 * lane + 1] == 0) ? 1 : 0;
        u32 e = (x32[lane] >> 7) & 0xff;
        int v = (e >= 110 && e <= 133) ? 1 : 0;
        unsigned long long bz = __ballot(z);
        unsigned long long bv = __ballot(v);
        if (lane == 0) {
            s_flags[0] = (__popcll(bz) == 64) ? 2 : 1;
            s_flags[1] = (__popcll(bv) >= 48) ? 1 : 0;
        }
    }
    __syncthreads();
    int isbf = s_flags[1];
    int i0 = blockIdx.x * 256 + tid;
    int stride = gridDim.x * 256;
    if (blockIdx.x == 0 && tid == 0) { flags[0] = s_flags[0]; flags[1] = isbf; }
    if (i0 < n) { deg[i0] = 1; cursor[i0] = 0; }       // self-loop
    if (i0 < nchunks) state[i0] = 0ULL;
    // W1 transpose in 64x64 tiles (blocks 0..63)
    if (blockIdx.x < 64) {
        int t = blockIdx.x;
        int tr = t >> 3, tc = t & 7;
        int rr = tid >> 2, cq = (tid & 3) * 16;
#pragma unroll
        for (int c = 0; c < 16; ++c)
            tile[cq + c][rr] = ldf(W1, (tr * 64 + rr) * 512 + tc * 64 + cq + c, isbf);
        __syncthreads();
#pragma unroll
        for (int c = 0; c < 16; ++c)
            w1t[(size_t)(tc * 64 + rr) * 512 + tr * 64 + cq + c] = f2bf(tile[rr][cq + c]);
    }
    for (int i = i0; i < 64 * 512; i += stride) {
        int nn = i >> 9, k = i & 511;
        w2t[i] = (nn < C_OUT) ? f2bf(ldf(W2, k * C_OUT + nn, isbf)) : (u16)0;
    }
    if (i0 < C_HID) b1f[i0] = ldf(b1, i0, isbf);
    if (i0 < C_OUT) b2f[i0] = ldf(b2, i0, isbf);
}

__global__ void k_deg(const int* __restrict__ ei, const int* __restrict__ flags,
                      int* deg, int E, int ecap, int n) {
    int e = blockIdx.x * 256 + threadIdx.x;
    if (e >= E) return;
    int st = flags[0];
    int cap = ecap * st - 1;
    u32 d = (u32)ei[imin((E + e) * st, cap)];
    if (d < (u32)n) atomicAdd(&deg[d], 1);
}

// ---------------- single-kernel scan: dinv + exclusive offs (lookback) ------
// state[c]: 0 = invalid; bit62 = aggregate ready; bit63 = prefix ready;
// low 32 bits = value. Blocks 0..nchunks-1, all co-resident (196 blocks).
__global__ __launch_bounds__(256) void k_scan(
    const int* __restrict__ deg, float* __restrict__ dinv, int* __restrict__ offs,
    u64* state, int n, int nchunks) {
    __shared__ int sh[256];
    __shared__ int s_prefix;
    int tid = threadIdx.x;
    int c = blockIdx.x;
    int i = c * 256 + tid;
    int dv = (i < n) ? deg[i] : 1;
    if (i < n) dinv[i] = rsqrtf((float)imax(dv, 1));
    int v = (i < n) ? dv - 1 : 0;
    sh[tid] = v;
    __syncthreads();
    for (int d = 1; d < 256; d <<= 1) {
        int add = (tid >= d) ? sh[tid - d] : 0;
        __syncthreads();
        sh[tid] += add;
        __syncthreads();
    }
    int total = sh[255];
    if (tid == 0) {
        atomicExch(&state[c], (1ULL << 62) | (u64)(u32)total);
        long long prefix = 0;
        int cc = c - 1;
        while (cc >= 0) {
            u64 s;
            do { s = atomicAdd(&state[cc], 0ULL); } while (s == 0ULL);
            prefix += (long long)(u32)s;
            if (s >> 63) break;
            --cc;
        }
        atomicExch(&state[c], (1ULL << 63) | (u64)(u32)(prefix + total));
        s_prefix = (int)prefix;
        if (c == nchunks - 1) offs[n] = (int)(prefix + total);
    }
    __syncthreads();
    int pfx = s_prefix;
    if (i < n) offs[i] = pfx + sh[tid] - v;   // exclusive
}

__global__ void k_sort(const int* __restrict__ ei, const int* __restrict__ flags,
                       const int* __restrict__ offs, int* cursor, int* csr,
                       int E, int ecap, int n) {
    int e = blockIdx.x * 256 + threadIdx.x;
    if (e >= E) return;
    int st = flags[0];
    int cap = ecap * st - 1;
    u32 d = (u32)ei[imin((E + e) * st, cap)];
    u32 s = (u32)ei[imin(e * st, cap)];
    if (d < (u32)n && s < (u32)n) {
        int pos = offs[d] + atomicAdd(&cursor[(int)d], 1);
        if ((u32)pos < (u32)E) csr[pos] = (int)s;
    }
}

// ---------------- GEMM1: 64x128 tile, BK=64, split-half LDS (R16) -----------
typedef __attribute__((address_space(1))) const u32 glds_src;
typedef __attribute__((address_space(3))) u32 glds_dst;

__global__ __launch_bounds__(256) void k_gemm128(
    const u16* __restrict__ xbf, const float* __restrict__ xf32,
    const int* __restrict__ flags, const u16* __restrict__ Bt,
    char* __restrict__ C, int M, int K, int ldc) {
    int isbf = flags[1];
    __shared__ __align__(16) u16 As0[64 * 32], As1[64 * 32];
    __shared__ __align__(16) u16 Bs0[128 * 32], Bs1[128 * 32];
    int tid = threadIdx.x;
    int wave = tid >> 6, lane = tid & 63;
    int quad = lane >> 4, lrow = lane & 15;
    int wrow = (wave & 1) * 32, wcol = (wave >> 1) * 64;

    int nwg = gridDim.x;
    int id = blockIdx.x;
    int q = nwg >> 3, r = nwg & 7;
    int xcd = id & 7, j8 = id >> 3;
    int wg = (xcd < r ? xcd * (q + 1) : r * (q + 1) + (xcd - r) * q) + j8;
    int row0 = (wg >> 2) * 64;
    int n0 = (wg & 3) * 128;

    int lr = lane >> 2;
    int lc = (lane & 3) * 8;
    int ar = row0 + wave * 16 + lr;
    int br = n0 + wave * 32 + lr;
    u16* As0_w = As0 + (wave * 16) * 32;
    u16* As1_w = As1 + (wave * 16) * 32;
    u16* Bs0_w = Bs0 + (wave * 32) * 32;
    u16* Bs1_w = Bs1 + (wave * 32) * 32;

    f32x4 acc[2][4] = {};
    int kTiles = K >> 6;   // BK=64
    for (int kt = 0; kt < kTiles; ++kt) {
        int k0 = kt * 64;
        int a0 = imin(ar, M - 1);
        if (isbf) {
            const u16* gA0 = xbf + (size_t)a0 * K + k0 + lc;
            __builtin_amdgcn_global_load_lds((glds_src*)gA0, (glds_dst*)As0_w, 16, 0, 0);
            __builtin_amdgcn_global_load_lds((glds_src*)(gA0 + 32), (glds_dst*)As1_w, 16, 0, 0);
        } else {
            const float* f0 = xf32 + (size_t)a0 * K + k0 + lc;
            float4 u0 = *(const float4*)(f0);
            float4 u1 = *(const float4*)(f0 + 4);
            float4 u2 = *(const float4*)(f0 + 32);
            float4 u3 = *(const float4*)(f0 + 36);
            *(u32x4*)(As0_w + lr * 32 + lc) = pk8(u0, u1);
            *(u32x4*)(As1_w + lr * 32 + lc) = pk8(u2, u3);
        }
        const u16* gB0 = Bt + (size_t)br * K + k0 + lc;
        const u16* gB1 = Bt + (size_t)(br + 16) * K + k0 + lc;
        __builtin_amdgcn_global_load_lds((glds_src*)gB0, (glds_dst*)Bs0_w, 16, 0, 0);
        __builtin_amdgcn_global_load_lds((glds_src*)gB1, (glds_dst*)(Bs0_w + 16 * 32), 16, 0, 0);
        __builtin_amdgcn_global_load_lds((glds_src*)(gB0 + 32), (glds_dst*)Bs1_w, 16, 0, 0);
        __builtin_amdgcn_global_load_lds((glds_src*)(gB1 + 32), (glds_dst*)(Bs1_w + 16 * 32), 16, 0, 0);
        __syncthreads();
#pragma unroll
        for (int ko = 0; ko < 2; ++ko) {
            const u16* Asrc = ko ? As1 : As0;
            const u16* Bsrc = ko ? Bs1 : Bs0;
            bf16x8 af[2], bfr[4];
#pragma unroll
            for (int i = 0; i < 2; ++i)
                af[i] = *(const bf16x8*)(Asrc + (wrow + i * 16 + lrow) * 32 + quad * 8);
#pragma unroll
            for (int j = 0; j < 4; ++j)
                bfr[j] = *(const bf16x8*)(Bsrc + (wcol + j * 16 + lrow) * 32 + quad * 8);
#pragma unroll
            for (int i = 0; i < 2; ++i)
#pragma unroll
                for (int j = 0; j < 4; ++j)
                    acc[i][j] = __builtin_amdgcn_mfma_f32_16x16x32_bf16(af[i], bfr[j],
                                                                        acc[i][j], 0, 0, 0);
        }
        __syncthreads();
    }
#pragma unroll
    for (int i = 0; i < 2; ++i)
#pragma unroll
        for (int j = 0; j < 4; ++j)
#pragma unroll
            for (int r2 = 0; r2 < 4; ++r2) {
                int row = row0 + wrow + i * 16 + quad * 4 + r2;
                int col = n0 + wcol + j * 16 + lrow;
                if (row < M) C[(size_t)row * ldc + col] = q8(acc[i][j][r2]);
            }
}

// ---------------- GEMM2: w2t-in-LDS, barrier-free A stream, bf16 out --------
#define B2ROW 520
__global__ __launch_bounds__(256) void k_gemm64(
    const u16* __restrict__ A, const u16* __restrict__ Bt, u16* __restrict__ Cout,
    int M, int K, int Ncols, int ldc) {
    __shared__ __align__(16) u16 Bsh[48 * B2ROW];
    int tid = threadIdx.x;
    int wave = tid >> 6, lane = tid & 63;
    int quad = lane >> 4, lrow = lane & 15;

    for (int i = tid; i < 48 * 64; i += 256) {
        int rw = i >> 6, cv = (i & 63) * 8;
        *(uint4*)(Bsh + rw * B2ROW + cv) = *(const uint4*)(Bt + (size_t)rw * 512 + cv);
    }
    __syncthreads();

    int row0 = blockIdx.x * 128 + wave * 32;
    int r0 = imin(row0 + lrow, M - 1);
    int r1 = imin(row0 + 16 + lrow, M - 1);
    const u16* a0p = A + (size_t)r0 * K + quad * 8;
    const u16* a1p = A + (size_t)r1 * K + quad * 8;
    const u16* b0p = Bsh + (0 * 16 + lrow) * B2ROW + quad * 8;
    const u16* b1p = Bsh + (1 * 16 + lrow) * B2ROW + quad * 8;
    const u16* b2p = Bsh + (2 * 16 + lrow) * B2ROW + quad * 8;

    f32x4 c00 = {}, c01 = {}, c02 = {};
    f32x4 c10 = {}, c11 = {}, c12 = {};
#pragma unroll 4
    for (int k0 = 0; k0 < C_HID; k0 += 32) {
        bf16x8 a0 = *(const bf16x8*)(a0p + k0);
        bf16x8 a1 = *(const bf16x8*)(a1p + k0);
        bf16x8 b0 = *(const bf16x8*)(b0p + k0);
        bf16x8 b1 = *(const bf16x8*)(b1p + k0);
        bf16x8 b2 = *(const bf16x8*)(b2p + k0);
        c00 = __builtin_amdgcn_mfma_f32_16x16x32_bf16(a0, b0, c00, 0, 0, 0);
        c01 = __builtin_amdgcn_mfma_f32_16x16x32_bf16(a0, b1, c01, 0, 0, 0);
        c02 = __builtin_amdgcn_mfma_f32_16x16x32_bf16(a0, b2, c02, 0, 0, 0);
        c10 = __builtin_amdgcn_mfma_f32_16x16x32_bf16(a1, b0, c10, 0, 0, 0);
        c11 = __builtin_amdgcn_mfma_f32_16x16x32_bf16(a1, b1, c11, 0, 0, 0);
        c12 = __builtin_amdgcn_mfma_f32_16x16x32_bf16(a1, b2, c12, 0, 0, 0);
    }
    f32x4 cc[2][3] = {{c00, c01, c02}, {c10, c11, c12}};
#pragma unroll
    for (int i = 0; i < 2; ++i)
#pragma unroll
        for (int t = 0; t < 3; ++t)
#pragma unroll
            for (int r = 0; r < 4; ++r) {
                int row = row0 + i * 16 + quad * 4 + r;
                int col = t * 16 + lrow;
                if (row < M && col < Ncols)
                    Cout[(size_t)row * ldc + col] = f2bf(cc[i][t][r]);
            }
}

// ---------------- agg1: hagg = ReLU(Anorm*h + b1), int8 in, bf16 out ----------------
__device__ __forceinline__ void accum8i(float* acc, uint2 p, float w) {
    int lo = (int)p.x, hi = (int)p.y;
    acc[0] += w * (float)(signed char)(lo);
    acc[1] += w * (float)(signed char)(lo >> 8);
    acc[2] += w * (float)(signed char)(lo >> 16);
    acc[3] += w * (float)(signed char)(lo >> 24);
    acc[4] += w * (float)(signed char)(hi);
    acc[5] += w * (float)(signed char)(hi >> 8);
    acc[6] += w * (float)(signed char)(hi >> 16);
    acc[7] += w * (float)(signed char)(hi >> 24);
}

__global__ __launch_bounds__(256) void k_agg1(
    const char* __restrict__ hq, const int* __restrict__ csr, const int* __restrict__ offs,
    const float* __restrict__ dinv, const float* __restrict__ b1f,
    u16* __restrict__ out, int n, int Etot) {
    int wave = threadIdx.x >> 6, lane = threadIdx.x & 63;
    int v = blockIdx.x * 4 + wave;
    if (v >= n) return;
    float dv = dinv[v];
    float wself = dv * dv * H_INV_SCALE;

    float acc[8] = {0.f, 0.f, 0.f, 0.f, 0.f, 0.f, 0.f, 0.f};
    uint2 hs = *(const uint2*)(hq + (size_t)v * C_HID + lane * 8);
    accum8i(acc, hs, wself);

    int e0 = imax(0, imin(offs[v], Etot));
    int e1 = imax(e0, imin(offs[v + 1], Etot));
    for (int base = e0; base < e1; base += 64) {
        int cnt = imin(64, e1 - base);
        int sreg = 0; float wreg = 0.f;
        if (lane < cnt) {
            u32 s = (u32)csr[base + lane];
            s = (s < (u32)n) ? s : 0u;
            sreg = (int)s;
            wreg = dv * dinv[s] * H_INV_SCALE;
        }
        int j = 0;
        for (; j + 16 <= cnt; j += 16) {
            int ss[16]; float ww[16]; uint2 pp[16];
#pragma unroll
            for (int t = 0; t < 16; ++t) {
                ss[t] = __shfl(sreg, j + t);
                ww[t] = __shfl(wreg, j + t);
            }
#pragma unroll
            for (int t = 0; t < 16; ++t)
                pp[t] = *(const uint2*)(hq + (size_t)ss[t] * C_HID + lane * 8);
#pragma unroll
            for (int t = 0; t < 16; ++t) accum8i(acc, pp[t], ww[t]);
        }
        for (; j + 8 <= cnt; j += 8) {
            int ss[8]; float ww[8]; uint2 pp[8];
#pragma unroll
            for (int t = 0; t < 8; ++t) {
                ss[t] = __shfl(sreg, j + t);
                ww[t] = __shfl(wreg, j + t);
            }
#pragma unroll
            for (int t = 0; t < 8; ++t)
                pp[t] = *(const uint2*)(hq + (size_t)ss[t] * C_HID + lane * 8);
#pragma unroll
            for (int t = 0; t < 8; ++t) accum8i(acc, pp[t], ww[t]);
        }
        for (; j + 4 <= cnt; j += 4) {
            int ss[4]; float ww[4]; uint2 pp[4];
#pragma unroll
            for (int t = 0; t < 4; ++t) {
                ss[t] = __shfl(sreg, j + t);
                ww[t] = __shfl(wreg, j + t);
            }
#pragma unroll
            for (int t = 0; t < 4; ++t)
                pp[t] = *(const uint2*)(hq + (size_t)ss[t] * C_HID + lane * 8);
#pragma unroll
            for (int t = 0; t < 4; ++t) accum8i(acc, pp[t], ww[t]);
        }
        for (; j < cnt; ++j) {
            int sj = __shfl(sreg, j);
            float wj = __shfl(wreg, j);
            uint2 pj = *(const uint2*)(hq + (size_t)sj * C_HID + lane * 8);
            accum8i(acc, pj, wj);
        }
    }

    float4 ba = *(const float4*)(b1f + lane * 8);
    float4 bb = *(const float4*)(b1f + lane * 8 + 4);
    float r0 = fmaxf(acc[0] + ba.x, 0.f), r1 = fmaxf(acc[1] + ba.y, 0.f);
    float r2 = fmaxf(acc[2] + ba.z, 0.f), r3 = fmaxf(acc[3] + ba.w, 0.f);
    float r4 = fmaxf(acc[4] + bb.x, 0.f), r5 = fmaxf(acc[5] + bb.y, 0.f);
    float r6 = fmaxf(acc[6] + bb.z, 0.f), r7 = fmaxf(acc[7] + bb.w, 0.f);
    u32x4 o;
    o.x = (u32)f2bf(r0) | ((u32)f2bf(r1) << 16);
    o.y = (u32)f2bf(r2) | ((u32)f2bf(r3) << 16);
    o.z = (u32)f2bf(r4) | ((u32)f2bf(r5) << 16);
    o.w = (u32)f2bf(r6) | ((u32)f2bf(r7) << 16);
    // nontemporal: don't let the 50MB output stream evict h from L2
    __builtin_nontemporal_store(o, (u32x4*)(out + (size_t)v * C_HID + lane * 8));
}

// ---------------- agg2 + bias + log_softmax: bf16 h2, 24 edges in flight ----------------
__global__ __launch_bounds__(256) void k_agg2(
    const u16* __restrict__ h2, const int* __restrict__ csr, const int* __restrict__ offs,
    const float* __restrict__ dinv, const float* __restrict__ b2f,
    const int* __restrict__ flags, void* __restrict__ out, int n, int Etot) {
    int wave = threadIdx.x >> 6, lane = threadIdx.x & 63;
    int v = blockIdx.x * 4 + wave;
    if (v >= n) return;
    float dv = dinv[v];

    int g = lane / 10;            // 0..6
    int f4 = lane - g * 10;       // 0..9
    bool active = (g < 6);

    float4 acc = make_float4(0.f, 0.f, 0.f, 0.f);
    if (g == 0) {
        uint2 pv = *(const uint2*)(h2 + (size_t)v * C_OUT + f4 * 4);
        float w = dv * dv;
        acc.x = w * bf2f((u16)pv.x); acc.y = w * bf2f((u16)(pv.x >> 16));
        acc.z = w * bf2f((u16)pv.y); acc.w = w * bf2f((u16)(pv.y >> 16));
    }

    int e0 = imax(0, imin(offs[v], Etot));
    int e1 = imax(e0, imin(offs[v + 1], Etot));
    for (int base = e0; base < e1; base += 64) {
        int cnt = imin(64, e1 - base);
        int sreg = 0; float wreg = 0.f;
        if (lane < cnt) {
            u32 s = (u32)csr[base + lane];
            s = (s < (u32)n) ? s : 0u;
            sreg = (int)s;
            wreg = dv * dinv[s];
        }
        for (int j = 0; j < cnt; j += 24) {
            uint2 p[4]; float w4[4];
#pragma unroll
            for (int t = 0; t < 4; ++t) {
                int jj = j + t * 6 + g;
                int idx = imin(jj, cnt - 1);
                int sj = __shfl(sreg, idx);
                float wj = __shfl(wreg, idx);
                w4[t] = (active && jj < cnt) ? wj : 0.f;
                p[t] = make_uint2(0, 0);
                if (active) p[t] = *(const uint2*)(h2 + (size_t)sj * C_OUT + f4 * 4);
            }
#pragma unroll
            for (int t = 0; t < 4; ++t) {
                acc.x += w4[t] * bf2f((u16)p[t].x);
                acc.y += w4[t] * bf2f((u16)(p[t].x >> 16));
                acc.z += w4[t] * bf2f((u16)p[t].y);
                acc.w += w4[t] * bf2f((u16)(p[t].y >> 16));
            }
        }
    }

    float4 t;
    t.x = __shfl(acc.x, lane + 30); t.y = __shfl(acc.y, lane + 30);
    t.z = __shfl(acc.z, lane + 30); t.w = __shfl(acc.w, lane + 30);
    if (lane < 30) { acc.x += t.x; acc.y += t.y; acc.z += t.z; acc.w += t.w; }
    float4 t1, t2;
    t1.x = __shfl(acc.x, lane + 10); t1.y = __shfl(acc.y, lane + 10);
    t1.z = __shfl(acc.z, lane + 10); t1.w = __shfl(acc.w, lane + 10);
    t2.x = __shfl(acc.x, lane + 20); t2.y = __shfl(acc.y, lane + 20);
    t2.z = __shfl(acc.z, lane + 20); t2.w = __shfl(acc.w, lane + 20);
    if (lane < 10) {
        acc.x += t1.x + t2.x; acc.y += t1.y + t2.y;
        acc.z += t1.z + t2.z; acc.w += t1.w + t2.w;
        acc.x += b2f[f4 * 4 + 0]; acc.y += b2f[f4 * 4 + 1];
        acc.z += b2f[f4 * 4 + 2]; acc.w += b2f[f4 * 4 + 3];
    }

    float m = -1e30f;
    if (lane < 10) m = fmaxf(fmaxf(acc.x, acc.y), fmaxf(acc.z, acc.w));
    for (int off = 32; off > 0; off >>= 1) m = fmaxf(m, __shfl_xor(m, off));
    float s = 0.f;
    if (lane < 10)
        s = expf(acc.x - m) + expf(acc.y - m) + expf(acc.z - m) + expf(acc.w - m);
    for (int off = 32; off > 0; off >>= 1) s += __shfl_xor(s, off);
    if (lane < 10) {
        float ls = m + logf(s);
        if (flags[1]) {
            ushort4 o;
            o.x = f2bf(acc.x - ls); o.y = f2bf(acc.y - ls);
            o.z = f2bf(acc.z - ls); o.w = f2bf(acc.w - ls);
            *(ushort4*)((u16*)out + (size_t)v * C_OUT + f4 * 4) = o;
        } else {
            float4 o = make_float4(acc.x - ls, acc.y - ls, acc.z - ls, acc.w - ls);
            *(float4*)((float*)out + (size_t)v * C_OUT + f4 * 4) = o;
        }
    }
}

// ---------------- launch ----------------

extern "C" void kernel_launch(void* const* d_in, const int* in_sizes, int n_in,
                              void* d_out, int out_size, void* d_ws, size_t ws_size,
                              hipStream_t stream) {
    const void* x = d_in[0];
    const int* ei = (const int*)d_in[1];
    const void* W1 = d_in[2];
    const void* b1 = d_in[3];
    const void* W2 = d_in[4];
    const void* b2 = d_in[5];

    const int N = out_size / C_OUT;
    const int Mx = in_sizes[0] / C_IN;
    const int M = (N < Mx) ? N : Mx;
    const int ECAP = in_sizes[1];
    const int E = ECAP / 2;

    char* p = (char*)d_ws;
    size_t used = 0;
    auto carve = [&](size_t bytes) -> void* {
        void* r = (void*)p;
        size_t b = (bytes + 255) & ~(size_t)255;
        p += b; used += b;
        return r;
    };
    int* flags = (int*)carve(256);
    int* deg = (int*)carve((size_t)N * 4);
    int* cursor = (int*)carve((size_t)N * 4);
    float* dinv = (float*)carve((size_t)N * 4);
    int* offs = (int*)carve((size_t)(N + 1) * 4);
    u64* state = (u64*)carve(4096);
    int* csr = (int*)carve((size_t)E * 4);
    u16* w1t = (u16*)carve((size_t)C_HID * C_IN * 2);
    u16* w2t = (u16*)carve((size_t)64 * C_HID * 2);
    float* b1f = (float*)carve(C_HID * 4);
    float* b2f = (float*)carve(256);
    u16* bufA = (u16*)carve((size_t)N * C_HID * 2);   // hagg
    u16* bufB = (u16*)carve((size_t)N * C_HID * 2);   // h_i8, then h2 (bf16)
    if (used > ws_size) return;

    char* h_i8 = (char*)bufB;
    u16* hagg = bufA;
    u16* h2 = bufB;

    const int NB = (N + 255) / 256;
    const int EB = (E + 255) / 256;

    k_initprep<<<NB, 256, 0, stream>>>((const u32*)x, ei, W1, b1, W2, b2,
                                       flags, deg, cursor, state,
                                       w1t, w2t, b1f, b2f, N, NB);
    k_deg<<<EB, 256, 0, stream>>>(ei, flags, deg, E, ECAP, N);
    k_scan<<<NB, 256, 0, stream>>>(deg, dinv, offs, state, N, NB);
    k_sort<<<EB, 256, 0, stream>>>(ei, flags, offs, cursor, csr, E, ECAP, N);

    int nbx = (M + 63) / 64;
    k_gemm128<<<nbx * 4, 256, 0, stream>>>((const u16*)x, (const float*)x, flags,
                                           w1t, h_i8, M, C_IN, C_HID);

    k_agg1<<<(N + 3) / 4, 256, 0, stream>>>(h_i8, csr, offs, dinv, b1f, hagg, N, E);

    k_gemm64<<<(M + 127) / 128, 256, 0, stream>>>(hagg, w2t, h2, N, C_HID, C_OUT, C_OUT);

    k_agg2<<<(N + 3) / 4, 256, 0, stream>>>(h2, csr, offs, dinv, b2f, flags, d_out, N, E);
}